// Round 1
// baseline (490.893 us; speedup 1.0000x reference)
//
#include <hip/hip_runtime.h>

using u16 = unsigned short;
using u32 = unsigned int;
typedef __bf16 bf16;
typedef bf16 bf16x8 __attribute__((ext_vector_type(8)));
typedef u16 u16x8 __attribute__((ext_vector_type(8)));
typedef u16 u16x4 __attribute__((ext_vector_type(4)));
typedef u32 u32x2 __attribute__((ext_vector_type(2)));
typedef float f32x4 __attribute__((ext_vector_type(4)));

// Problem constants: B=4, T=2048, E=1024, H=16, D=64
// Inputs fp32, output fp32. Internals bf16 (MFMA).
#define LDSS 72   // padded stride, attn P buffer only (GEMM tiles are unpadded for global_load_lds)

__device__ __forceinline__ u16 f2bf(float f) {
  u32 u = __builtin_bit_cast(u32, f);
  u += 0x7FFFu + ((u >> 16) & 1u);   // round-to-nearest-even
  return (u16)(u >> 16);
}

// truncating pack: two fp32 -> two bf16 in ONE v_perm_b32 (softmax P only;
// trunc error <= 2^-8 relative, inside the absmax budget)
__device__ __forceinline__ u32 packtrunc(float lo, float hi) {
  return __builtin_amdgcn_perm(__builtin_bit_cast(u32, hi),
                               __builtin_bit_cast(u32, lo), 0x07060302u);
}

__device__ __forceinline__ float fexp2(float x) {
#if __has_builtin(__builtin_amdgcn_exp2f)
  return __builtin_amdgcn_exp2f(x);   // bare v_exp_f32 (args here are never denormal-critical)
#else
  return exp2f(x);
#endif
}

__device__ __forceinline__ bf16x8 ldfrag(const u16* p) {
  return __builtin_bit_cast(bf16x8, *(const u16x8*)p);
}

__device__ __forceinline__ u16x8 cvt8(const float* p) {
  float4 a = ((const float4*)p)[0];
  float4 b = ((const float4*)p)[1];
  u16x8 o;
  o[0] = f2bf(a.x); o[1] = f2bf(a.y); o[2] = f2bf(a.z); o[3] = f2bf(a.w);
  o[4] = f2bf(b.x); o[5] = f2bf(b.y); o[6] = f2bf(b.z); o[7] = f2bf(b.w);
  return o;
}

// async global->LDS, 16 B per lane; LDS dest = wave-uniform base + lane*16
__device__ __forceinline__ void gll16(const u16* g, u16* l) {
  __builtin_amdgcn_global_load_lds(
      (const __attribute__((address_space(1))) u32*)g,
      (__attribute__((address_space(3))) u32*)l, 16, 0, 0);
}

// ---------------------------------------------------------------------------
// fp32 -> bf16 convert (one-time; feeds global_load_lds GEMMs)
// ---------------------------------------------------------------------------
__global__ __launch_bounds__(256) void cvt_bf16(
    const float* __restrict__ src, u16* __restrict__ dst, int n8) {
  int i = blockIdx.x * 256 + threadIdx.x;
  const int stride = gridDim.x * 256;
  for (; i < n8; i += stride)
    ((u16x8*)dst)[i] = cvt8(&src[(size_t)i * 8]);
}

// ---------------------------------------------------------------------------
// QKV projection (m97-style): qkv[m][f] = sum_c x[m][c] * W_qkv[f][c]
// ---------------------------------------------------------------------------
__global__ __launch_bounds__(256) void qkv_gemm(
    const u16* __restrict__ X, const u16* __restrict__ W,
    u16* __restrict__ Qw, u16* __restrict__ Kw, u16* __restrict__ Vtw) {
  __shared__ u16 As[128 * 64];   // unpadded: required by global_load_lds layout
  __shared__ u16 Bs[128 * 64];
  const int tid = threadIdx.x;
  const int lane = tid & 63;
  const int wv = tid >> 6;
  const int quad = lane >> 4;
  const int l16 = lane & 15;
  const int m0 = (wv >> 1) * 64;
  const int n0 = (wv & 1) * 64;
  const int rowA0 = blockIdx.y * 128;
  const int rowB0 = blockIdx.x * 128;

  f32x4 acc[4][4] = {};

  for (int kt = 0; kt < 1024; kt += 64) {
#pragma unroll
    for (int t = 0; t < 4; ++t) {
      int base = t * 256 + wv * 64;        // wave-uniform chunk base
      int idx = base + lane;               // per-lane chunk (16 B)
      int row = idx >> 3, c = (idx & 7) * 8;
      gll16(&X[(size_t)(rowA0 + row) * 1024 + kt + c], &As[base * 8]);
      gll16(&W[(size_t)(rowB0 + row) * 1024 + kt + c], &Bs[base * 8]);
    }
    __syncthreads();
#pragma unroll
    for (int kk = 0; kk < 64; kk += 32) {
      bf16x8 af[4], bfr[4];
#pragma unroll
      for (int i = 0; i < 4; ++i)
        af[i] = ldfrag(&As[(m0 + i * 16 + l16) * 64 + kk + quad * 8]);
#pragma unroll
      for (int j = 0; j < 4; ++j)
        bfr[j] = ldfrag(&Bs[(n0 + j * 16 + l16) * 64 + kk + quad * 8]);
#pragma unroll
      for (int i = 0; i < 4; ++i)
#pragma unroll
        for (int j = 0; j < 4; ++j)
          acc[i][j] = __builtin_amdgcn_mfma_f32_16x16x32_bf16(af[i], bfr[j], acc[i][j], 0, 0, 0);
    }
    __syncthreads();
  }

  const float QSCALE = 0.125f * 1.4426950408889634f;  // D^-0.5 * log2(e)
#pragma unroll
  for (int i = 0; i < 4; ++i)
#pragma unroll
    for (int j = 0; j < 4; ++j)
#pragma unroll
      for (int r = 0; r < 4; ++r) {
        int m = rowA0 + m0 + i * 16 + quad * 4 + r;   // C row
        int f = rowB0 + n0 + j * 16 + l16;            // C col
        float v = acc[i][j][r];
        int bb = m >> 11, t = m & 2047;
        int part = f >> 10, fi = f & 1023;
        int h = fi >> 6, d = fi & 63;
        if (part == 0) {
          Qw[((size_t)(bb * 16 + h) * 2048 + t) * 64 + d] = f2bf(v * QSCALE);
        } else if (part == 1) {
          Kw[((size_t)(bb * 16 + h) * 2048 + t) * 64 + d] = f2bf(v);
        } else {
          Vtw[((size_t)(bb * 16 + h) * 64 + d) * 2048 + t] = f2bf(v);
        }
      }
}

// ---------------------------------------------------------------------------
// Flash attention, transposed-S. 4 waves per block, one (bh, q-stripe) per
// block; the 4 waves split the key-tile range (flash-decode style) and merge
// partial (m, l, O^T) through LDS. Longest per-wave chain drops 32 -> 8
// tiles, and the 4x-oversubscribed grid (4096 blocks x 4 waves vs 16
// waves/CU resident) lets the HW backfill keep CUs full to the end.
// ---------------------------------------------------------------------------
__global__ __launch_bounds__(256, 4) void attn_kernel(
    const u16* __restrict__ Qw, const u16* __restrict__ Kw,
    const u16* __restrict__ Vtw, u16* __restrict__ Ao) {
  __shared__ u16 pws[4][32 * LDSS];  // per-wave P^T buffer [q 32][key 64]
  __shared__ float Ob[64][33];       // merged O^T accumulator [d][q], +1 pad
  __shared__ float2 mlb[32];         // per-q running (m, l)
  const int tid = threadIdx.x;
  const int lane = tid & 63;
  const int wid = tid >> 6;
  const int quad = lane >> 4;
  const int l16 = lane & 15;
  const int s = 63 - (blockIdx.x >> 6);   // q-stripe (longest dispatched first)
  const int bh = blockIdx.x & 63;
  const u16* Qb = Qw + (size_t)bh * 2048 * 64;
  const u16* Kb = Kw + (size_t)bh * 2048 * 64;
  const u16* Vb = Vtw + (size_t)bh * 64 * 2048;
  const int qrow0 = s * 32;
  u16* Pb = pws[wid];

  // Q B-frags (n = q = l16, k = d = quad*8+j), held for the whole block
  bf16x8 qf[2][2];
#pragma unroll
  for (int i = 0; i < 2; ++i)
#pragma unroll
    for (int kk = 0; kk < 2; ++kk)
      qf[i][kk] = ldfrag(&Qb[(size_t)(qrow0 + i * 16 + l16) * 64 + kk * 32 + quad * 8]);

  f32x4 oacc[4][2] = {};          // partial O^T: [dblk][qblk]
  float mst[2] = {-INFINITY, -INFINITY};
  float lst[2] = {0.f, 0.f};

  // contiguous key-tile split across the 4 waves; wave 3 always owns the
  // diagonal tile (so the merge accumulator's m is always finite).
  const int nkt = (s >> 1) + 1;   // tiles covering keys <= qrow0+31
  const int kt0 = (wid * nkt) >> 2;
  const int kt1 = ((wid + 1) * nkt) >> 2;

  for (int kt = kt0; kt < kt1; ++kt) {
    const u16* Kt = Kb + (size_t)kt * 64 * 64;

    // issue K frags AND V frags up front: V consumed only after softmax,
    // so its latency hides behind ~600 VALU cycles.
    bf16x8 kf[2][4], vf[2][4];
#pragma unroll
    for (int kk = 0; kk < 2; ++kk)
#pragma unroll
      for (int j = 0; j < 4; ++j) {
        kf[kk][j] = ldfrag(&Kt[(size_t)(j * 16 + l16) * 64 + kk * 32 + quad * 8]);
        vf[kk][j] = ldfrag(&Vb[(size_t)(j * 16 + l16) * 2048 + kt * 64 + kk * 32 + quad * 8]);
      }

    // S^T = K . Q^T  (64 keys x 32 q)
    f32x4 sv[2][4] = {};           // [qblk][keyblk]
    __builtin_amdgcn_s_setprio(1);
#pragma unroll
    for (int kk = 0; kk < 2; ++kk)
#pragma unroll
      for (int i = 0; i < 2; ++i)
#pragma unroll
        for (int j = 0; j < 4; ++j)
          sv[i][j] = __builtin_amdgcn_mfma_f32_16x16x32_bf16(kf[kk][j], qf[i][kk], sv[i][j], 0, 0, 0);
    __builtin_amdgcn_s_setprio(0);

    // causal mask: key > q  (C-layout: row=key=quad*4+r, col=q=l16)
    if (kt * 64 + 63 > qrow0) {
#pragma unroll
      for (int i = 0; i < 2; ++i) {
        int q = qrow0 + i * 16 + l16;
#pragma unroll
        for (int j = 0; j < 4; ++j)
#pragma unroll
          for (int r = 0; r < 4; ++r)
            if (kt * 64 + j * 16 + quad * 4 + r > q) sv[i][j][r] = -INFINITY;
      }
    }

    // online softmax: per-lane q-column; cross-quad combine via 2 shuffles
#pragma unroll
    for (int i = 0; i < 2; ++i) {
      float mx = -INFINITY;
#pragma unroll
      for (int j = 0; j < 4; ++j)
#pragma unroll
        for (int r = 0; r < 4; ++r) mx = fmaxf(mx, sv[i][j][r]);
      mx = fmaxf(mx, __shfl_xor(mx, 16));
      mx = fmaxf(mx, __shfl_xor(mx, 32));
      float mnew = fmaxf(mst[i], mx);
      if (!__all(mnew == mst[i])) {      // wave-uniform: rescale only on max update
        float alpha = fexp2(mst[i] - mnew);
        lst[i] *= alpha;
#pragma unroll
        for (int d = 0; d < 4; ++d) oacc[d][i] *= alpha;
        mst[i] = mnew;
      }
      float rs = 0.f;
#pragma unroll
      for (int j = 0; j < 4; ++j) {
        float p0 = fexp2(sv[i][j][0] - mst[i]);
        float p1 = fexp2(sv[i][j][1] - mst[i]);
        float p2 = fexp2(sv[i][j][2] - mst[i]);
        float p3 = fexp2(sv[i][j][3] - mst[i]);
        rs += (p0 + p1) + (p2 + p3);
        u32x2 pk;
        pk[0] = packtrunc(p0, p1);
        pk[1] = packtrunc(p2, p3);
        // P^T row = q (i*16+l16), cols = 4 consecutive keys -> b64 write
        *(u32x2*)&Pb[(i * 16 + l16) * LDSS + j * 16 + quad * 4] = pk;
      }
      rs += __shfl_xor(rs, 16);
      rs += __shfl_xor(rs, 32);
      lst[i] += rs;
    }

    // O^T += V^T . P^T   (A = V^T frags already resident, B = P^T from own LDS)
#pragma unroll
    for (int kk = 0; kk < 2; ++kk) {
      bf16x8 pf[2];
#pragma unroll
      for (int i = 0; i < 2; ++i)
        pf[i] = ldfrag(&Pb[(i * 16 + l16) * LDSS + kk * 32 + quad * 8]);
      __builtin_amdgcn_s_setprio(1);
#pragma unroll
      for (int d = 0; d < 4; ++d)
#pragma unroll
        for (int i = 0; i < 2; ++i)
          oacc[d][i] = __builtin_amdgcn_mfma_f32_16x16x32_bf16(vf[kk][d], pf[i], oacc[d][i], 0, 0, 0);
      __builtin_amdgcn_s_setprio(0);
    }
  }

  // ---- cross-wave merge of partial (m, l, O^T) ----
  // wave 3 (always non-empty, owns diagonal) initializes the accumulator
  if (wid == 3) {
#pragma unroll
    for (int i = 0; i < 2; ++i)
#pragma unroll
      for (int d = 0; d < 4; ++d)
#pragma unroll
        for (int r = 0; r < 4; ++r)
          Ob[d * 16 + quad * 4 + r][i * 16 + l16] = oacc[d][i][r];
    if (quad == 0) {
      mlb[l16] = make_float2(mst[0], lst[0]);
      mlb[16 + l16] = make_float2(mst[1], lst[1]);
    }
  }
  __syncthreads();
#pragma unroll
  for (int w = 2; w >= 0; --w) {
    if (wid == w && kt1 > kt0) {    // empty waves contribute nothing
      float2 a0 = mlb[l16], a1 = mlb[16 + l16];
      float Mn0 = fmaxf(a0.x, mst[0]);
      float Mn1 = fmaxf(a1.x, mst[1]);
      float e0o = fexp2(a0.x - Mn0), e0n = fexp2(mst[0] - Mn0);
      float e1o = fexp2(a1.x - Mn1), e1n = fexp2(mst[1] - Mn1);
#pragma unroll
      for (int d = 0; d < 4; ++d)
#pragma unroll
        for (int r = 0; r < 4; ++r) {
          int row = d * 16 + quad * 4 + r;
          Ob[row][l16]      = Ob[row][l16]      * e0o + oacc[d][0][r] * e0n;
          Ob[row][16 + l16] = Ob[row][16 + l16] * e1o + oacc[d][1][r] * e1n;
        }
      if (quad == 0) {
        mlb[l16]      = make_float2(Mn0, a0.y * e0o + lst[0] * e0n);
        mlb[16 + l16] = make_float2(Mn1, a1.y * e1o + lst[1] * e1n);
      }
    }
    __syncthreads();
  }

  // epilogue: wave 0 normalizes + stores (coalesced bf16, [B,T,E])
  if (wid == 0) {
    const int bb = bh >> 4, h = bh & 15;
    const int row = lane >> 1, half = lane & 1;
    const int t = qrow0 + row;
    const float inv = 1.f / mlb[row].y;
#pragma unroll
    for (int c = 0; c < 4; ++c) {
      u16x8 v;
#pragma unroll
      for (int e = 0; e < 8; ++e)
        v[e] = f2bf(Ob[half * 32 + c * 8 + e][row] * inv);
      *(u16x8*)&Ao[((size_t)(bb * 2048 + t)) * 1024 + h * 64 + half * 32 + c * 8] = v;
    }
  }
}

// ---------------------------------------------------------------------------
// Output projection (m97-style): out[m][o] = sum_c att[m][c] * W_out[o][c]
// ---------------------------------------------------------------------------
__global__ __launch_bounds__(256) void out_gemm(
    const u16* __restrict__ A, const u16* __restrict__ W,
    float* __restrict__ O) {
  __shared__ u16 As[128 * 64];
  __shared__ u16 Bs[128 * 64];
  const int tid = threadIdx.x;
  const int lane = tid & 63;
  const int wv = tid >> 6;
  const int quad = lane >> 4;
  const int l16 = lane & 15;
  const int m0 = (wv >> 1) * 64;
  const int n0 = (wv & 1) * 64;
  const int rowA0 = blockIdx.y * 128;
  const int rowB0 = blockIdx.x * 128;

  f32x4 acc[4][4] = {};

  for (int kt = 0; kt < 1024; kt += 64) {
#pragma unroll
    for (int t = 0; t < 4; ++t) {
      int base = t * 256 + wv * 64;
      int idx = base + lane;
      int row = idx >> 3, c = (idx & 7) * 8;
      gll16(&A[(size_t)(rowA0 + row) * 1024 + kt + c], &As[base * 8]);
      gll16(&W[(size_t)(rowB0 + row) * 1024 + kt + c], &Bs[base * 8]);
    }
    __syncthreads();
#pragma unroll
    for (int kk = 0; kk < 64; kk += 32) {
      bf16x8 af[4], bfr[4];
#pragma unroll
      for (int i = 0; i < 4; ++i)
        af[i] = ldfrag(&As[(m0 + i * 16 + l16) * 64 + kk + quad * 8]);
#pragma unroll
      for (int j = 0; j < 4; ++j)
        bfr[j] = ldfrag(&Bs[(n0 + j * 16 + l16) * 64 + kk + quad * 8]);
#pragma unroll
      for (int i = 0; i < 4; ++i)
#pragma unroll
        for (int j = 0; j < 4; ++j)
          acc[i][j] = __builtin_amdgcn_mfma_f32_16x16x32_bf16(af[i], bfr[j], acc[i][j], 0, 0, 0);
    }
    __syncthreads();
  }

#pragma unroll
  for (int i = 0; i < 4; ++i)
#pragma unroll
    for (int j = 0; j < 4; ++j)
#pragma unroll
      for (int r = 0; r < 4; ++r) {
        int m = rowA0 + m0 + i * 16 + quad * 4 + r;
        int o = rowB0 + n0 + j * 16 + l16;
        O[(size_t)m * 1024 + o] = acc[i][j][r];   // fp32 out
      }
}

extern "C" void kernel_launch(void* const* d_in, const int* in_sizes, int n_in,
                              void* d_out, int out_size, void* d_ws, size_t ws_size,
                              hipStream_t stream) {
  (void)in_sizes; (void)n_in; (void)out_size; (void)ws_size;
  const float* x    = (const float*)d_in[0];   // [4,2048,1024] fp32
  const float* Wqkv = (const float*)d_in[1];   // [3072,1024]  fp32
  const float* Wout = (const float*)d_in[2];   // [1024,1024]  fp32
  float* out = (float*)d_out;                  // [4,2048,1024] fp32
  u16* ws = (u16*)d_ws;

  const size_t NX   = (size_t)4 * 2048 * 1024;  // 8,388,608
  const size_t NQKV = (size_t)3072 * 1024;      // 3,145,728
  const size_t NOUT = (size_t)1024 * 1024;      // 1,048,576
  const size_t SZ   = NX;

  u16* Xc    = ws;               // bf16 inputs
  u16* Wqkvc = Xc + NX;
  u16* Woutc = Wqkvc + NQKV;
  u16* Qw    = Woutc + NOUT;     // [B,H,T,D] bf16, pre-scaled 0.125*log2e
  u16* Kw    = Qw + SZ;          // [B,H,T,D] bf16
  u16* Vtw   = Kw + SZ;          // [B,H,D,T] bf16 (transposed)
  u16* Ao    = Vtw + SZ;         // [B,T,E]   bf16

  cvt_bf16<<<dim3(1024), 256, 0, stream>>>(x, Xc, (int)(NX / 8));
  cvt_bf16<<<dim3(384), 256, 0, stream>>>(Wqkv, Wqkvc, (int)(NQKV / 8));
  cvt_bf16<<<dim3(128), 256, 0, stream>>>(Wout, Woutc, (int)(NOUT / 8));

  qkv_gemm<<<dim3(24, 64), 256, 0, stream>>>(Xc, Wqkvc, Qw, Kw, Vtw);
  attn_kernel<<<dim3(4096), 256, 0, stream>>>(Qw, Kw, Vtw, Ao);
  out_gemm<<<dim3(8, 64), 256, 0, stream>>>(Ao, Woutc, out);
}

// Round 2
// 358.779 us; speedup vs baseline: 1.3682x; 1.3682x over previous
//
#include <hip/hip_runtime.h>

using u16 = unsigned short;
using u32 = unsigned int;
typedef __bf16 bf16;
typedef bf16 bf16x8 __attribute__((ext_vector_type(8)));
typedef u16 u16x8 __attribute__((ext_vector_type(8)));
typedef u16 u16x4 __attribute__((ext_vector_type(4)));
typedef u32 u32x2 __attribute__((ext_vector_type(2)));
typedef float f32x4 __attribute__((ext_vector_type(4)));

// Problem constants: B=4, T=2048, E=1024, H=16, D=64
// Inputs fp32, output fp32. Internals bf16 (MFMA).
#define LDSS 72   // padded stride, attn P buffer only (GEMM tiles are unpadded for global_load_lds)

__device__ __forceinline__ u16 f2bf(float f) {
  u32 u = __builtin_bit_cast(u32, f);
  u += 0x7FFFu + ((u >> 16) & 1u);   // round-to-nearest-even
  return (u16)(u >> 16);
}

// truncating pack: two fp32 -> two bf16 in ONE v_perm_b32 (softmax P only;
// trunc error <= 2^-8 relative, inside the absmax budget)
__device__ __forceinline__ u32 packtrunc(float lo, float hi) {
  return __builtin_amdgcn_perm(__builtin_bit_cast(u32, hi),
                               __builtin_bit_cast(u32, lo), 0x07060302u);
}

__device__ __forceinline__ float fexp2(float x) {
#if __has_builtin(__builtin_amdgcn_exp2f)
  return __builtin_amdgcn_exp2f(x);   // bare v_exp_f32 (args here are never denormal-critical)
#else
  return exp2f(x);
#endif
}

__device__ __forceinline__ bf16x8 ldfrag(const u16* p) {
  return __builtin_bit_cast(bf16x8, *(const u16x8*)p);
}

__device__ __forceinline__ u16x8 cvt8(const float* p) {
  float4 a = ((const float4*)p)[0];
  float4 b = ((const float4*)p)[1];
  u16x8 o;
  o[0] = f2bf(a.x); o[1] = f2bf(a.y); o[2] = f2bf(a.z); o[3] = f2bf(a.w);
  o[4] = f2bf(b.x); o[5] = f2bf(b.y); o[6] = f2bf(b.z); o[7] = f2bf(b.w);
  return o;
}

// async global->LDS, 16 B per lane; LDS dest = wave-uniform base + lane*16
__device__ __forceinline__ void gll16(const u16* g, u16* l) {
  __builtin_amdgcn_global_load_lds(
      (const __attribute__((address_space(1))) u32*)g,
      (__attribute__((address_space(3))) u32*)l, 16, 0, 0);
}

// ---------------------------------------------------------------------------
// fp32 -> bf16 convert (one-time; feeds global_load_lds GEMMs)
// ---------------------------------------------------------------------------
__global__ __launch_bounds__(256) void cvt_bf16(
    const float* __restrict__ src, u16* __restrict__ dst, int n8) {
  int i = blockIdx.x * 256 + threadIdx.x;
  const int stride = gridDim.x * 256;
  for (; i < n8; i += stride)
    ((u16x8*)dst)[i] = cvt8(&src[(size_t)i * 8]);
}

// ---------------------------------------------------------------------------
// QKV projection (m97-style): qkv[m][f] = sum_c x[m][c] * W_qkv[f][c]
// ---------------------------------------------------------------------------
__global__ __launch_bounds__(256) void qkv_gemm(
    const u16* __restrict__ X, const u16* __restrict__ W,
    u16* __restrict__ Qw, u16* __restrict__ Kw, u16* __restrict__ Vtw) {
  __shared__ u16 As[128 * 64];   // unpadded: required by global_load_lds layout
  __shared__ u16 Bs[128 * 64];
  const int tid = threadIdx.x;
  const int lane = tid & 63;
  const int wv = tid >> 6;
  const int quad = lane >> 4;
  const int l16 = lane & 15;
  const int m0 = (wv >> 1) * 64;
  const int n0 = (wv & 1) * 64;
  const int rowA0 = blockIdx.y * 128;
  const int rowB0 = blockIdx.x * 128;

  f32x4 acc[4][4] = {};

  for (int kt = 0; kt < 1024; kt += 64) {
#pragma unroll
    for (int t = 0; t < 4; ++t) {
      int base = t * 256 + wv * 64;        // wave-uniform chunk base
      int idx = base + lane;               // per-lane chunk (16 B)
      int row = idx >> 3, c = (idx & 7) * 8;
      gll16(&X[(size_t)(rowA0 + row) * 1024 + kt + c], &As[base * 8]);
      gll16(&W[(size_t)(rowB0 + row) * 1024 + kt + c], &Bs[base * 8]);
    }
    __syncthreads();
#pragma unroll
    for (int kk = 0; kk < 64; kk += 32) {
      bf16x8 af[4], bfr[4];
#pragma unroll
      for (int i = 0; i < 4; ++i)
        af[i] = ldfrag(&As[(m0 + i * 16 + l16) * 64 + kk + quad * 8]);
#pragma unroll
      for (int j = 0; j < 4; ++j)
        bfr[j] = ldfrag(&Bs[(n0 + j * 16 + l16) * 64 + kk + quad * 8]);
#pragma unroll
      for (int i = 0; i < 4; ++i)
#pragma unroll
        for (int j = 0; j < 4; ++j)
          acc[i][j] = __builtin_amdgcn_mfma_f32_16x16x32_bf16(af[i], bfr[j], acc[i][j], 0, 0, 0);
    }
    __syncthreads();
  }

  const float QSCALE = 0.125f * 1.4426950408889634f;  // D^-0.5 * log2(e)
#pragma unroll
  for (int i = 0; i < 4; ++i)
#pragma unroll
    for (int j = 0; j < 4; ++j)
#pragma unroll
      for (int r = 0; r < 4; ++r) {
        int m = rowA0 + m0 + i * 16 + quad * 4 + r;   // C row
        int f = rowB0 + n0 + j * 16 + l16;            // C col
        float v = acc[i][j][r];
        int bb = m >> 11, t = m & 2047;
        int part = f >> 10, fi = f & 1023;
        int h = fi >> 6, d = fi & 63;
        if (part == 0) {
          Qw[((size_t)(bb * 16 + h) * 2048 + t) * 64 + d] = f2bf(v * QSCALE);
        } else if (part == 1) {
          Kw[((size_t)(bb * 16 + h) * 2048 + t) * 64 + d] = f2bf(v);
        } else {
          Vtw[((size_t)(bb * 16 + h) * 64 + d) * 2048 + t] = f2bf(v);
        }
      }
}

// ---------------------------------------------------------------------------
// Flash attention, transposed-S. 4 waves per block, one (bh, q-stripe) per
// block; the 4 waves split the key-tile range (flash-decode style) and merge
// partial (m, l, O^T) through LDS. Longest per-wave chain drops 32 -> 8
// tiles vs the 1-wave version, and the 4x-oversubscribed grid lets HW
// backfill keep CUs full to the end.
// NOTE: no min-waves in launch_bounds — round-1's (256,4) capped VGPR at a
// level that spilled the whole loop body to scratch (WRITE_SIZE 649 MB).
// V-frag loads moved after QK^T so kf/vf live ranges don't overlap; peak
// pressure ~120 regs -> no spill, still 4 blocks/CU at <=128 VGPR.
// ---------------------------------------------------------------------------
__global__ __launch_bounds__(256) void attn_kernel(
    const u16* __restrict__ Qw, const u16* __restrict__ Kw,
    const u16* __restrict__ Vtw, u16* __restrict__ Ao) {
  __shared__ u16 pws[4][32 * LDSS];  // per-wave P^T buffer [q 32][key 64]
  __shared__ float Ob[64][33];       // merged O^T accumulator [d][q], +1 pad
  __shared__ float2 mlb[32];         // per-q running (m, l)
  const int tid = threadIdx.x;
  const int lane = tid & 63;
  const int wid = tid >> 6;
  const int quad = lane >> 4;
  const int l16 = lane & 15;
  const int s = 63 - (blockIdx.x >> 6);   // q-stripe (longest dispatched first)
  const int bh = blockIdx.x & 63;
  const u16* Qb = Qw + (size_t)bh * 2048 * 64;
  const u16* Kb = Kw + (size_t)bh * 2048 * 64;
  const u16* Vb = Vtw + (size_t)bh * 64 * 2048;
  const int qrow0 = s * 32;
  u16* Pb = pws[wid];

  // Q B-frags (n = q = l16, k = d = quad*8+j), held for the whole block
  bf16x8 qf[2][2];
#pragma unroll
  for (int i = 0; i < 2; ++i)
#pragma unroll
    for (int kk = 0; kk < 2; ++kk)
      qf[i][kk] = ldfrag(&Qb[(size_t)(qrow0 + i * 16 + l16) * 64 + kk * 32 + quad * 8]);

  f32x4 oacc[4][2] = {};          // partial O^T: [dblk][qblk]
  float mst[2] = {-INFINITY, -INFINITY};
  float lst[2] = {0.f, 0.f};

  // contiguous key-tile split across the 4 waves; wave 3 always owns the
  // diagonal tile (so the merge accumulator's m is always finite).
  const int nkt = (s >> 1) + 1;   // tiles covering keys <= qrow0+31
  const int kt0 = (wid * nkt) >> 2;
  const int kt1 = ((wid + 1) * nkt) >> 2;

  for (int kt = kt0; kt < kt1; ++kt) {
    const u16* Kt = Kb + (size_t)kt * 64 * 64;

    // K frags only (V comes after QK^T so kf/vf don't overlap in registers)
    bf16x8 kf[2][4];
#pragma unroll
    for (int kk = 0; kk < 2; ++kk)
#pragma unroll
      for (int j = 0; j < 4; ++j)
        kf[kk][j] = ldfrag(&Kt[(size_t)(j * 16 + l16) * 64 + kk * 32 + quad * 8]);

    // S^T = K . Q^T  (64 keys x 32 q)
    f32x4 sv[2][4] = {};           // [qblk][keyblk]
    __builtin_amdgcn_s_setprio(1);
#pragma unroll
    for (int kk = 0; kk < 2; ++kk)
#pragma unroll
      for (int i = 0; i < 2; ++i)
#pragma unroll
        for (int j = 0; j < 4; ++j)
          sv[i][j] = __builtin_amdgcn_mfma_f32_16x16x32_bf16(kf[kk][j], qf[i][kk], sv[i][j], 0, 0, 0);
    __builtin_amdgcn_s_setprio(0);
    // keep V loads BELOW the QK^T cluster (don't let the scheduler hoist
    // them up and re-overlap kf+vf live ranges -> spill)
    __builtin_amdgcn_sched_barrier(0);

    // V frags: issued here, consumed only after softmax (~600 VALU cycles)
    bf16x8 vf[2][4];
#pragma unroll
    for (int kk = 0; kk < 2; ++kk)
#pragma unroll
      for (int j = 0; j < 4; ++j)
        vf[kk][j] = ldfrag(&Vb[(size_t)(j * 16 + l16) * 2048 + kt * 64 + kk * 32 + quad * 8]);

    // causal mask: key > q  (C-layout: row=key=quad*4+r, col=q=l16)
    if (kt * 64 + 63 > qrow0) {
#pragma unroll
      for (int i = 0; i < 2; ++i) {
        int q = qrow0 + i * 16 + l16;
#pragma unroll
        for (int j = 0; j < 4; ++j)
#pragma unroll
          for (int r = 0; r < 4; ++r)
            if (kt * 64 + j * 16 + quad * 4 + r > q) sv[i][j][r] = -INFINITY;
      }
    }

    // online softmax: per-lane q-column; cross-quad combine via 2 shuffles
#pragma unroll
    for (int i = 0; i < 2; ++i) {
      float mx = -INFINITY;
#pragma unroll
      for (int j = 0; j < 4; ++j)
#pragma unroll
        for (int r = 0; r < 4; ++r) mx = fmaxf(mx, sv[i][j][r]);
      mx = fmaxf(mx, __shfl_xor(mx, 16));
      mx = fmaxf(mx, __shfl_xor(mx, 32));
      float mnew = fmaxf(mst[i], mx);
      if (!__all(mnew == mst[i])) {      // wave-uniform: rescale only on max update
        float alpha = fexp2(mst[i] - mnew);
        lst[i] *= alpha;
#pragma unroll
        for (int d = 0; d < 4; ++d) oacc[d][i] *= alpha;
        mst[i] = mnew;
      }
      float rs = 0.f;
#pragma unroll
      for (int j = 0; j < 4; ++j) {
        float p0 = fexp2(sv[i][j][0] - mst[i]);
        float p1 = fexp2(sv[i][j][1] - mst[i]);
        float p2 = fexp2(sv[i][j][2] - mst[i]);
        float p3 = fexp2(sv[i][j][3] - mst[i]);
        rs += (p0 + p1) + (p2 + p3);
        u32x2 pk;
        pk[0] = packtrunc(p0, p1);
        pk[1] = packtrunc(p2, p3);
        // P^T row = q (i*16+l16), cols = 4 consecutive keys -> b64 write
        *(u32x2*)&Pb[(i * 16 + l16) * LDSS + j * 16 + quad * 4] = pk;
      }
      rs += __shfl_xor(rs, 16);
      rs += __shfl_xor(rs, 32);
      lst[i] += rs;
    }

    // O^T += V^T . P^T   (A = V^T frags, B = P^T from own LDS)
#pragma unroll
    for (int kk = 0; kk < 2; ++kk) {
      bf16x8 pf[2];
#pragma unroll
      for (int i = 0; i < 2; ++i)
        pf[i] = ldfrag(&Pb[(i * 16 + l16) * LDSS + kk * 32 + quad * 8]);
      __builtin_amdgcn_s_setprio(1);
#pragma unroll
      for (int d = 0; d < 4; ++d)
#pragma unroll
        for (int i = 0; i < 2; ++i)
          oacc[d][i] = __builtin_amdgcn_mfma_f32_16x16x32_bf16(vf[kk][d], pf[i], oacc[d][i], 0, 0, 0);
      __builtin_amdgcn_s_setprio(0);
    }
  }

  // ---- cross-wave merge of partial (m, l, O^T) ----
  // wave 3 (always non-empty, owns diagonal) initializes the accumulator
  if (wid == 3) {
#pragma unroll
    for (int i = 0; i < 2; ++i)
#pragma unroll
      for (int d = 0; d < 4; ++d)
#pragma unroll
        for (int r = 0; r < 4; ++r)
          Ob[d * 16 + quad * 4 + r][i * 16 + l16] = oacc[d][i][r];
    if (quad == 0) {
      mlb[l16] = make_float2(mst[0], lst[0]);
      mlb[16 + l16] = make_float2(mst[1], lst[1]);
    }
  }
  __syncthreads();
#pragma unroll
  for (int w = 2; w >= 0; --w) {
    if (wid == w && kt1 > kt0) {    // empty waves contribute nothing
      float2 a0 = mlb[l16], a1 = mlb[16 + l16];
      float Mn0 = fmaxf(a0.x, mst[0]);
      float Mn1 = fmaxf(a1.x, mst[1]);
      float e0o = fexp2(a0.x - Mn0), e0n = fexp2(mst[0] - Mn0);
      float e1o = fexp2(a1.x - Mn1), e1n = fexp2(mst[1] - Mn1);
#pragma unroll
      for (int d = 0; d < 4; ++d)
#pragma unroll
        for (int r = 0; r < 4; ++r) {
          int row = d * 16 + quad * 4 + r;
          Ob[row][l16]      = Ob[row][l16]      * e0o + oacc[d][0][r] * e0n;
          Ob[row][16 + l16] = Ob[row][16 + l16] * e1o + oacc[d][1][r] * e1n;
        }
      if (quad == 0) {
        mlb[l16]      = make_float2(Mn0, a0.y * e0o + lst[0] * e0n);
        mlb[16 + l16] = make_float2(Mn1, a1.y * e1o + lst[1] * e1n);
      }
    }
    __syncthreads();
  }

  // epilogue: wave 0 normalizes + stores (coalesced bf16, [B,T,E])
  if (wid == 0) {
    const int bb = bh >> 4, h = bh & 15;
    const int row = lane >> 1, half = lane & 1;
    const int t = qrow0 + row;
    const float inv = 1.f / mlb[row].y;
#pragma unroll
    for (int c = 0; c < 4; ++c) {
      u16x8 v;
#pragma unroll
      for (int e = 0; e < 8; ++e)
        v[e] = f2bf(Ob[half * 32 + c * 8 + e][row] * inv);
      *(u16x8*)&Ao[((size_t)(bb * 2048 + t)) * 1024 + h * 64 + half * 32 + c * 8] = v;
    }
  }
}

// ---------------------------------------------------------------------------
// Output projection (m97-style): out[m][o] = sum_c att[m][c] * W_out[o][c]
// ---------------------------------------------------------------------------
__global__ __launch_bounds__(256) void out_gemm(
    const u16* __restrict__ A, const u16* __restrict__ W,
    float* __restrict__ O) {
  __shared__ u16 As[128 * 64];
  __shared__ u16 Bs[128 * 64];
  const int tid = threadIdx.x;
  const int lane = tid & 63;
  const int wv = tid >> 6;
  const int quad = lane >> 4;
  const int l16 = lane & 15;
  const int m0 = (wv >> 1) * 64;
  const int n0 = (wv & 1) * 64;
  const int rowA0 = blockIdx.y * 128;
  const int rowB0 = blockIdx.x * 128;

  f32x4 acc[4][4] = {};

  for (int kt = 0; kt < 1024; kt += 64) {
#pragma unroll
    for (int t = 0; t < 4; ++t) {
      int base = t * 256 + wv * 64;
      int idx = base + lane;
      int row = idx >> 3, c = (idx & 7) * 8;
      gll16(&A[(size_t)(rowA0 + row) * 1024 + kt + c], &As[base * 8]);
      gll16(&W[(size_t)(rowB0 + row) * 1024 + kt + c], &Bs[base * 8]);
    }
    __syncthreads();
#pragma unroll
    for (int kk = 0; kk < 64; kk += 32) {
      bf16x8 af[4], bfr[4];
#pragma unroll
      for (int i = 0; i < 4; ++i)
        af[i] = ldfrag(&As[(m0 + i * 16 + l16) * 64 + kk + quad * 8]);
#pragma unroll
      for (int j = 0; j < 4; ++j)
        bfr[j] = ldfrag(&Bs[(n0 + j * 16 + l16) * 64 + kk + quad * 8]);
#pragma unroll
      for (int i = 0; i < 4; ++i)
#pragma unroll
        for (int j = 0; j < 4; ++j)
          acc[i][j] = __builtin_amdgcn_mfma_f32_16x16x32_bf16(af[i], bfr[j], acc[i][j], 0, 0, 0);
    }
    __syncthreads();
  }

#pragma unroll
  for (int i = 0; i < 4; ++i)
#pragma unroll
    for (int j = 0; j < 4; ++j)
#pragma unroll
      for (int r = 0; r < 4; ++r) {
        int m = rowA0 + m0 + i * 16 + quad * 4 + r;
        int o = rowB0 + n0 + j * 16 + l16;
        O[(size_t)m * 1024 + o] = acc[i][j][r];   // fp32 out
      }
}

extern "C" void kernel_launch(void* const* d_in, const int* in_sizes, int n_in,
                              void* d_out, int out_size, void* d_ws, size_t ws_size,
                              hipStream_t stream) {
  (void)in_sizes; (void)n_in; (void)out_size; (void)ws_size;
  const float* x    = (const float*)d_in[0];   // [4,2048,1024] fp32
  const float* Wqkv = (const float*)d_in[1];   // [3072,1024]  fp32
  const float* Wout = (const float*)d_in[2];   // [1024,1024]  fp32
  float* out = (float*)d_out;                  // [4,2048,1024] fp32
  u16* ws = (u16*)d_ws;

  const size_t NX   = (size_t)4 * 2048 * 1024;  // 8,388,608
  const size_t NQKV = (size_t)3072 * 1024;      // 3,145,728
  const size_t NOUT = (size_t)1024 * 1024;      // 1,048,576
  const size_t SZ   = NX;

  u16* Xc    = ws;               // bf16 inputs
  u16* Wqkvc = Xc + NX;
  u16* Woutc = Wqkvc + NQKV;
  u16* Qw    = Woutc + NOUT;     // [B,H,T,D] bf16, pre-scaled 0.125*log2e
  u16* Kw    = Qw + SZ;          // [B,H,T,D] bf16
  u16* Vtw   = Kw + SZ;          // [B,H,D,T] bf16 (transposed)
  u16* Ao    = Vtw + SZ;         // [B,T,E]   bf16

  cvt_bf16<<<dim3(1024), 256, 0, stream>>>(x, Xc, (int)(NX / 8));
  cvt_bf16<<<dim3(384), 256, 0, stream>>>(Wqkv, Wqkvc, (int)(NQKV / 8));
  cvt_bf16<<<dim3(128), 256, 0, stream>>>(Wout, Woutc, (int)(NOUT / 8));

  qkv_gemm<<<dim3(24, 64), 256, 0, stream>>>(Xc, Wqkvc, Qw, Kw, Vtw);
  attn_kernel<<<dim3(4096), 256, 0, stream>>>(Qw, Kw, Vtw, Ao);
  out_gemm<<<dim3(8, 64), 256, 0, stream>>>(Ao, Woutc, out);
}